// Round 5
// baseline (39.984 us; speedup 1.0000x reference)
//
#include <hip/hip_runtime.h>

// Problem constants (from reference)
#define N_NODES 100000
#define PAD_DEG 32
#define BATCH 16384
#define K 11
#define F 128

// DIAGNOSTIC ROUND: R4 kernel body executed TWICE per block (pass loop with
// memory clobber so loads are re-issued). Doubles the dispatch duration so our
// kernel surfaces in the rocprof top-5 (above the 40 us harness fills),
// giving us FETCH_SIZE / VALUBusy / Occupancy for OUR dispatch, and a
// warm-pass-vs-cold-pass timing comparison. Output written identically in
// both passes -> deterministic, correct.
__global__ __launch_bounds__(256, 3) void WeightedAggregator_89489938580181_kernel(
    const float* __restrict__ emb,   // [N_NODES, F]
    const int*   __restrict__ samp,  // [BATCH, K]
    const int*   __restrict__ adj,   // [N_NODES, PAD_DEG]
    float*       __restrict__ out)   // [BATCH, F]
{
    const int lane = threadIdx.x & 63;
    const int wid  = __builtin_amdgcn_readfirstlane(threadIdx.x >> 6);
    const int wave = blockIdx.x * 4 + wid;   // global wave id
    const int r0   = wave * 4;               // first of 4 batch rows

    const int q = lane >> 4;      // which row this lane serves
    const int d = lane & 15;      // within-row lane index

#pragma unroll 1
    for (int pass = 0; pass < 2; ++pass) {
        // prevent CSE of the gathers across passes
        asm volatile("" ::: "memory");

        // ---- sampled node ids for all 4 rows (wave-uniform scalar loads) ----
        int s0[K], s1[K], s2[K], s3[K];
#pragma unroll
        for (int v = 0; v < K; ++v) s0[v] = samp[(r0 + 0) * K + v];
#pragma unroll
        for (int v = 0; v < K; ++v) s1[v] = samp[(r0 + 1) * K + v];
#pragma unroll
        for (int v = 0; v < K; ++v) s2[v] = samp[(r0 + 2) * K + v];
#pragma unroll
        for (int v = 0; v < K; ++v) s3[v] = samp[(r0 + 3) * K + v];

        // per-lane selected node ids: my row's sample v (2-level cndmask tree)
        int ssel[K];
#pragma unroll
        for (int v = 0; v < K; ++v) {
            const int t01 = (lane & 16) ? s1[v] : s0[v];
            const int t23 = (lane & 16) ? s3[v] : s2[v];
            ssel[v] = (lane & 32) ? t23 : t01;
        }

        // ---- issue ALL gathers up front ----
        int2 a[K];
#pragma unroll
        for (int p = 0; p < K; ++p)
            a[p] = *reinterpret_cast<const int2*>(
                &adj[(size_t)ssel[p] * PAD_DEG + d * 2]);

        float4 e0[K], e1[K];
#pragma unroll
        for (int v = 0; v < K; ++v) {
            const float* base = &emb[(size_t)ssel[v] * F];
            e0[v] = *reinterpret_cast<const float4*>(base + d * 4);
            e1[v] = *reinterpret_cast<const float4*>(base + d * 4 + 64);
        }

        // ---- membership counts via ballot (4 rows per ballot) ----
        int cnt[K];
#pragma unroll
        for (int v = 0; v < K; ++v) cnt[v] = 0;

        const int sh = q * 16;        // my row's 16-bit slice of the ballot
#pragma unroll
        for (int p = 0; p < K; ++p) {
#pragma unroll
            for (int v = 0; v < K; ++v) {
                const unsigned long long m =
                    __ballot(a[p].x == ssel[v] || a[p].y == ssel[v]);
                cnt[v] += (int)(((unsigned)(m >> sh) & 0xFFFFu) != 0);
            }
        }

        // ---- weights: w[v] = cnt[v] / sum(cnt)  (BETA = 1.0) ----
        int total = 0;
#pragma unroll
        for (int v = 0; v < K; ++v) total += cnt[v];
        const float inv = 1.0f / (float)total;   // >= 11 (self-loop)

        // ---- weighted sum on prefetched fragments ----
        float4 acc0 = make_float4(0.f, 0.f, 0.f, 0.f);
        float4 acc1 = make_float4(0.f, 0.f, 0.f, 0.f);
#pragma unroll
        for (int v = 0; v < K; ++v) {
            const float w = (float)cnt[v] * inv;
            acc0.x = fmaf(w, e0[v].x, acc0.x);
            acc0.y = fmaf(w, e0[v].y, acc0.y);
            acc0.z = fmaf(w, e0[v].z, acc0.z);
            acc0.w = fmaf(w, e0[v].w, acc0.w);
            acc1.x = fmaf(w, e1[v].x, acc1.x);
            acc1.y = fmaf(w, e1[v].y, acc1.y);
            acc1.z = fmaf(w, e1[v].z, acc1.z);
            acc1.w = fmaf(w, e1[v].w, acc1.w);
        }

        // ---- store: row = r0+q, two contiguous 256 B segments per row ----
        const int row = r0 + q;
        float* obase = &out[(size_t)row * F];
        *reinterpret_cast<float4*>(obase + d * 4)      = acc0;
        *reinterpret_cast<float4*>(obase + d * 4 + 64) = acc1;
    }
}

extern "C" void kernel_launch(void* const* d_in, const int* in_sizes, int n_in,
                              void* d_out, int out_size, void* d_ws, size_t ws_size,
                              hipStream_t stream) {
    const float* emb  = (const float*)d_in[0];
    const int*   samp = (const int*)d_in[1];
    const int*   adj  = (const int*)d_in[2];
    float*       outp = (float*)d_out;

    const int rows_per_block = 16;                // 4 waves x 4 rows
    dim3 grid(BATCH / rows_per_block);            // 1024 blocks
    dim3 block(256);
    WeightedAggregator_89489938580181_kernel<<<grid, block, 0, stream>>>(
        emb, samp, adj, outp);
}

// Round 6
// 25.951 us; speedup vs baseline: 1.5408x; 1.5408x over previous
//
#include <hip/hip_runtime.h>

// Problem constants (from reference)
#define N_NODES 100000
#define PAD_DEG 32
#define BATCH 16384
#define K 11
#define F 128

// One wave (64 lanes) per block, FOUR batch rows per wave: quarter
// q = lane>>4 owns row block*4+q, d = lane&15 is the within-row lane.
//  - adj gather p: int2 per lane -> 16 lanes cover the 32-slot adj row;
//    one instruction loads 4 rows' adj lists (4 x 128 B segments).
//  - ballot(a.x==ssel[v] || a.y==ssel[v]): bits [16q,16q+16) give row q's
//    membership of sample v in neighbor p's adj list.
//  - emb gather v: two float4 per lane covering row halves.
//  - store: two float4 per lane, 4 x 256 B contiguous segments per instr.
// 64-thread blocks (1 wave) x 4096 blocks: finest dispatch granularity to
// minimize the end-of-grid occupancy tail (R5 counters: avg occupancy ~ half
// of max with 4-wave blocks).
__global__ __launch_bounds__(64, 8) void WeightedAggregator_89489938580181_kernel(
    const float* __restrict__ emb,   // [N_NODES, F]
    const int*   __restrict__ samp,  // [BATCH, K]
    const int*   __restrict__ adj,   // [N_NODES, PAD_DEG]
    float*       __restrict__ out)   // [BATCH, F]
{
    const int lane = threadIdx.x & 63;
    const int r0   = blockIdx.x * 4;         // first of 4 batch rows

    const int q = lane >> 4;      // which row this lane serves
    const int d = lane & 15;      // within-row lane index

    // ---- sampled node ids for all 4 rows (wave-uniform scalar loads) ----
    int s0[K], s1[K], s2[K], s3[K];
#pragma unroll
    for (int v = 0; v < K; ++v) s0[v] = samp[(r0 + 0) * K + v];
#pragma unroll
    for (int v = 0; v < K; ++v) s1[v] = samp[(r0 + 1) * K + v];
#pragma unroll
    for (int v = 0; v < K; ++v) s2[v] = samp[(r0 + 2) * K + v];
#pragma unroll
    for (int v = 0; v < K; ++v) s3[v] = samp[(r0 + 3) * K + v];

    // per-lane selected node ids: my row's sample v (2-level cndmask tree)
    int ssel[K];
#pragma unroll
    for (int v = 0; v < K; ++v) {
        const int t01 = (lane & 16) ? s1[v] : s0[v];
        const int t23 = (lane & 16) ? s3[v] : s2[v];
        ssel[v] = (lane & 32) ? t23 : t01;
    }

    // ---- issue adj gathers FIRST (ballots depend only on these; the
    // compiler can start the ballot phase at vmcnt(22) with emb in flight) ----
    int2 a[K];
#pragma unroll
    for (int p = 0; p < K; ++p)
        a[p] = *reinterpret_cast<const int2*>(
            &adj[(size_t)ssel[p] * PAD_DEG + d * 2]);

    // embeddings: two float4/lane (row halves), 4 rows per instruction
    float4 e0[K], e1[K];
#pragma unroll
    for (int v = 0; v < K; ++v) {
        const float* base = &emb[(size_t)ssel[v] * F];
        e0[v] = *reinterpret_cast<const float4*>(base + d * 4);
        e1[v] = *reinterpret_cast<const float4*>(base + d * 4 + 64);
    }

    // ---- membership counts via ballot (4 rows per ballot) ----
    int cnt[K];
#pragma unroll
    for (int v = 0; v < K; ++v) cnt[v] = 0;

    const int sh = q * 16;        // my row's 16-bit slice of the ballot
#pragma unroll
    for (int p = 0; p < K; ++p) {
#pragma unroll
        for (int v = 0; v < K; ++v) {
            const unsigned long long m =
                __ballot(a[p].x == ssel[v] || a[p].y == ssel[v]);
            cnt[v] += (int)(((unsigned)(m >> sh) & 0xFFFFu) != 0);
        }
    }

    // ---- weights: w[v] = cnt[v] / sum(cnt)  (BETA = 1.0) ----
    int total = 0;
#pragma unroll
    for (int v = 0; v < K; ++v) total += cnt[v];
    const float inv = 1.0f / (float)total;   // >= 11 (self-loop in adj slot 0)

    // ---- weighted sum on prefetched fragments ----
    float4 acc0 = make_float4(0.f, 0.f, 0.f, 0.f);
    float4 acc1 = make_float4(0.f, 0.f, 0.f, 0.f);
#pragma unroll
    for (int v = 0; v < K; ++v) {
        const float w = (float)cnt[v] * inv;
        acc0.x = fmaf(w, e0[v].x, acc0.x);
        acc0.y = fmaf(w, e0[v].y, acc0.y);
        acc0.z = fmaf(w, e0[v].z, acc0.z);
        acc0.w = fmaf(w, e0[v].w, acc0.w);
        acc1.x = fmaf(w, e1[v].x, acc1.x);
        acc1.y = fmaf(w, e1[v].y, acc1.y);
        acc1.z = fmaf(w, e1[v].z, acc1.z);
        acc1.w = fmaf(w, e1[v].w, acc1.w);
    }

    // ---- store: row = r0+q, two contiguous 256 B segments per row ----
    const int row = r0 + q;
    float* obase = &out[(size_t)row * F];
    *reinterpret_cast<float4*>(obase + d * 4)      = acc0;
    *reinterpret_cast<float4*>(obase + d * 4 + 64) = acc1;
}

extern "C" void kernel_launch(void* const* d_in, const int* in_sizes, int n_in,
                              void* d_out, int out_size, void* d_ws, size_t ws_size,
                              hipStream_t stream) {
    const float* emb  = (const float*)d_in[0];
    const int*   samp = (const int*)d_in[1];
    const int*   adj  = (const int*)d_in[2];
    float*       outp = (float*)d_out;

    const int rows_per_block = 4;                 // 1 wave x 4 rows
    dim3 grid(BATCH / rows_per_block);            // 4096 blocks
    dim3 block(64);
    WeightedAggregator_89489938580181_kernel<<<grid, block, 0, stream>>>(
        emb, samp, adj, outp);
}

// Round 7
// 23.873 us; speedup vs baseline: 1.6748x; 1.0870x over previous
//
#include <hip/hip_runtime.h>

// Problem constants (from reference)
#define N_NODES 100000
#define PAD_DEG 32
#define BATCH 16384
#define K 11
#define F 128

// One wave (64 lanes) handles FOUR batch rows: quarter q = lane>>4 owns
// row wave*4+q, d = lane&15 is the within-row lane.
//  - adj gather p: int2 per lane -> 16 lanes cover the 32-slot adj row;
//    one instruction loads 4 rows' adj lists (4 x 128 B segments).
//  - ballot(a.x==ssel[v] || a.y==ssel[v]): bits [16q,16q+16) give row q's
//    membership of sample v in neighbor p's adj list.
//  - emb gather v: two float4 per lane covering row halves; one instruction
//    loads 4 x 256 B contiguous segments.
//  - store: two float4 per lane, 4 x 256 B contiguous segments per instr.
// 4 waves (256 threads) per block -> 16 rows/block, 1024 blocks.
// (Best measured config: 24.09 us. 1-wave blocks regressed to 25.95; 2-rows/
//  wave was 24.35 — the op is pinned by the per-CU random-gather concurrency
//  cap, insensitive to these structurings.)
__global__ __launch_bounds__(256, 3) void WeightedAggregator_89489938580181_kernel(
    const float* __restrict__ emb,   // [N_NODES, F]
    const int*   __restrict__ samp,  // [BATCH, K]
    const int*   __restrict__ adj,   // [N_NODES, PAD_DEG]
    float*       __restrict__ out)   // [BATCH, F]
{
    const int lane = threadIdx.x & 63;
    const int wid  = __builtin_amdgcn_readfirstlane(threadIdx.x >> 6);
    const int wave = blockIdx.x * 4 + wid;   // global wave id
    const int r0   = wave * 4;               // first of 4 batch rows

    // ---- sampled node ids for all 4 rows (wave-uniform scalar loads) ----
    int s0[K], s1[K], s2[K], s3[K];
#pragma unroll
    for (int v = 0; v < K; ++v) s0[v] = samp[(r0 + 0) * K + v];
#pragma unroll
    for (int v = 0; v < K; ++v) s1[v] = samp[(r0 + 1) * K + v];
#pragma unroll
    for (int v = 0; v < K; ++v) s2[v] = samp[(r0 + 2) * K + v];
#pragma unroll
    for (int v = 0; v < K; ++v) s3[v] = samp[(r0 + 3) * K + v];

    const int q = lane >> 4;      // which row this lane serves
    const int d = lane & 15;      // within-row lane index

    // per-lane selected node ids: my row's sample v (2-level cndmask tree)
    int ssel[K];
#pragma unroll
    for (int v = 0; v < K; ++v) {
        const int t01 = (lane & 16) ? s1[v] : s0[v];
        const int t23 = (lane & 16) ? s3[v] : s2[v];
        ssel[v] = (lane & 32) ? t23 : t01;
    }

    // ---- issue ALL gathers up front ----
    // adjacency: int2/lane, 16 lanes cover 32 slots, 4 rows per instruction
    int2 a[K];
#pragma unroll
    for (int p = 0; p < K; ++p)
        a[p] = *reinterpret_cast<const int2*>(
            &adj[(size_t)ssel[p] * PAD_DEG + d * 2]);

    // embeddings: two float4/lane (row halves), 4 rows per instruction
    float4 e0[K], e1[K];
#pragma unroll
    for (int v = 0; v < K; ++v) {
        const float* base = &emb[(size_t)ssel[v] * F];
        e0[v] = *reinterpret_cast<const float4*>(base + d * 4);
        e1[v] = *reinterpret_cast<const float4*>(base + d * 4 + 64);
    }

    // ---- membership counts via ballot (4 rows per ballot) ----
    int cnt[K];
#pragma unroll
    for (int v = 0; v < K; ++v) cnt[v] = 0;

    const int sh = q * 16;        // my row's 16-bit slice of the ballot
#pragma unroll
    for (int p = 0; p < K; ++p) {
#pragma unroll
        for (int v = 0; v < K; ++v) {
            const unsigned long long m =
                __ballot(a[p].x == ssel[v] || a[p].y == ssel[v]);
            cnt[v] += (int)(((unsigned)(m >> sh) & 0xFFFFu) != 0);
        }
    }

    // ---- weights: w[v] = cnt[v] / sum(cnt)  (BETA = 1.0) ----
    int total = 0;
#pragma unroll
    for (int v = 0; v < K; ++v) total += cnt[v];
    const float inv = 1.0f / (float)total;   // >= 11 (self-loop in adj slot 0)

    // ---- weighted sum on prefetched fragments ----
    float4 acc0 = make_float4(0.f, 0.f, 0.f, 0.f);
    float4 acc1 = make_float4(0.f, 0.f, 0.f, 0.f);
#pragma unroll
    for (int v = 0; v < K; ++v) {
        const float w = (float)cnt[v] * inv;
        acc0.x = fmaf(w, e0[v].x, acc0.x);
        acc0.y = fmaf(w, e0[v].y, acc0.y);
        acc0.z = fmaf(w, e0[v].z, acc0.z);
        acc0.w = fmaf(w, e0[v].w, acc0.w);
        acc1.x = fmaf(w, e1[v].x, acc1.x);
        acc1.y = fmaf(w, e1[v].y, acc1.y);
        acc1.z = fmaf(w, e1[v].z, acc1.z);
        acc1.w = fmaf(w, e1[v].w, acc1.w);
    }

    // ---- store: row = r0+q, two contiguous 256 B segments per row ----
    const int row = r0 + q;
    float* obase = &out[(size_t)row * F];
    *reinterpret_cast<float4*>(obase + d * 4)      = acc0;
    *reinterpret_cast<float4*>(obase + d * 4 + 64) = acc1;
}

extern "C" void kernel_launch(void* const* d_in, const int* in_sizes, int n_in,
                              void* d_out, int out_size, void* d_ws, size_t ws_size,
                              hipStream_t stream) {
    const float* emb  = (const float*)d_in[0];
    const int*   samp = (const int*)d_in[1];
    const int*   adj  = (const int*)d_in[2];
    float*       outp = (float*)d_out;

    const int rows_per_block = 16;                // 4 waves x 4 rows
    dim3 grid(BATCH / rows_per_block);            // 1024 blocks
    dim3 block(256);
    WeightedAggregator_89489938580181_kernel<<<grid, block, 0, stream>>>(
        emb, samp, adj, outp);
}